// Round 3
// baseline (716.844 us; speedup 1.0000x reference)
//
#include <hip/hip_runtime.h>

#define ENC_T 20
#define DEC_T 30

typedef _Float16 f16x8 __attribute__((ext_vector_type(8)));
typedef float f32x16 __attribute__((ext_vector_type(16)));

// LDS layout (bytes): union region for W tables, restaged enc->dec
#define WOFF   0        // [256][64] f16 swizzled: Whh_enc, then Wdec=Wih_dec+Whh_dec (32KB)
#define WXOFF  32768    // [256][16] f16: enc x-tile table (w0,w1,bias,0...) (8KB)
#define EMBOFF 40960    // [32][64]  f16: W_emb rows 0,1 + zeros (4KB)
#define HOFF   45056    // 4 waves x [32][64] f16 h buffers (16KB)
#define LDS_BYTES 61440

__device__ __forceinline__ float sigf(float x) {
    return __builtin_amdgcn_rcpf(1.0f + __builtin_amdgcn_exp2f(-1.44269504088896f * x));
}
__device__ __forceinline__ float tanhf_fast(float x) {
    return 2.0f * __builtin_amdgcn_rcpf(1.0f + __builtin_amdgcn_exp2f(-2.88539008177793f * x)) - 1.0f;
}

__global__ __launch_bounds__(256, 2)
void lstm_s2s_kernel(const float* __restrict__ xin,
                     const float* __restrict__ Wih_e, const float* __restrict__ Whh_e,
                     const float* __restrict__ bih_e, const float* __restrict__ bhh_e,
                     const float* __restrict__ Wih_d, const float* __restrict__ Whh_d,
                     const float* __restrict__ bih_d, const float* __restrict__ bhh_d,
                     const float* __restrict__ Wemb, const float* __restrict__ bemb,
                     float* __restrict__ out, int B)
{
    __shared__ __align__(16) unsigned char lds[LDS_BYTES];
    const int tid  = threadIdx.x;
    const int wid  = tid >> 6;
    const int lane = tid & 63;
    const int cl   = lane & 31;   // column-within-tile / A row
    const int hi   = lane >> 5;   // k-half select
    const int r0   = blockIdx.x * 128 + wid * 32;
    if (r0 >= B) return;

    // ---------------- stage encoder tables ----------------
    for (int i = tid; i < 256 * 64; i += 256) {
        int n = i >> 6, k = i & 63;
        *(_Float16*)(lds + WOFF + n * 128 + (((k * 2) ^ ((n & 7) << 4)))) = (_Float16)Whh_e[i];
    }
    {   // x-tile table: k0=Wih[:,0], k1=Wih[:,1], k2=b_ih+b_hh, rest 0
        int n = tid;
        float b  = bih_e[n] + bhh_e[n];
        float w0 = Wih_e[n * 2 + 0], w1 = Wih_e[n * 2 + 1];
        #pragma unroll
        for (int k = 0; k < 16; ++k) {
            float v = (k == 0) ? w0 : (k == 1) ? w1 : (k == 2) ? b : 0.0f;
            *(_Float16*)(lds + WXOFF + n * 32 + (((k * 2) ^ ((n & 1) << 4)))) = (_Float16)v;
        }
    }
    for (int i = tid; i < 4 * 32 * 64; i += 256)   // zero h buffers (h0 = 0)
        *(_Float16*)(lds + HOFF + i * 2) = (_Float16)0.0f;
    __syncthreads();

    unsigned char* hbuf = lds + HOFF + wid * 4096;

    float c[32];
    #pragma unroll
    for (int i = 0; i < 32; ++i) c[i] = 0.0f;

    f32x16 acc[8];
    f16x8  haf[4];

    // ---------------- encoder: 20 steps ----------------
    for (int t = 0; t < ENC_T; ++t) {
        // A fragment for x-tile: [x0, x1, 1, 0...] on low lanes, zeros on high lanes
        f16x8 xa;
        #pragma unroll
        for (int e = 0; e < 8; ++e) xa[e] = (_Float16)0.0f;
        if (hi == 0) {
            const float* xp = xin + (size_t)(r0 + cl) * (ENC_T * 2) + t * 2;
            xa[0] = (_Float16)xp[0];
            xa[1] = (_Float16)xp[1];
            xa[2] = (_Float16)1.0f;
        }
        #pragma unroll
        for (int t8 = 0; t8 < 8; ++t8) {
            int n = t8 * 32 + cl;
            f16x8 wx = *(const f16x8*)(lds + WXOFF + n * 32 + ((hi * 16) ^ ((n & 1) << 4)));
            f32x16 z;
            #pragma unroll
            for (int q = 0; q < 16; ++q) z[q] = 0.0f;
            acc[t8] = __builtin_amdgcn_mfma_f32_32x32x16_f16(xa, wx, z, 0, 0, 0);
        }
        #pragma unroll
        for (int kk = 0; kk < 4; ++kk)
            haf[kk] = *(const f16x8*)(hbuf + cl * 128 + ((kk * 32 + hi * 16) ^ ((cl & 7) << 4)));
        #pragma unroll
        for (int kk = 0; kk < 4; ++kk) {
            #pragma unroll
            for (int t8 = 0; t8 < 8; ++t8) {
                int n = t8 * 32 + cl;
                f16x8 wb = *(const f16x8*)(lds + WOFF + n * 128 + ((kk * 32 + hi * 16) ^ ((n & 7) << 4)));
                acc[t8] = __builtin_amdgcn_mfma_f32_32x32x16_f16(haf[kk], wb, acc[t8], 0, 0, 0);
            }
        }
        // elementwise LSTM cell; lane owns j in {cl, cl+32} x 16 rows
        #pragma unroll
        for (int js = 0; js < 2; ++js) {
            int j = cl + js * 32;
            #pragma unroll
            for (int r = 0; r < 16; ++r) {
                float iv = acc[0 + js][r];
                float fv = acc[2 + js][r];
                float gv = acc[4 + js][r];
                float ov = acc[6 + js][r];
                float cc = c[js * 16 + r];
                float ct = sigf(fv) * cc + sigf(iv) * tanhf_fast(gv);
                c[js * 16 + r] = ct;
                float hv = sigf(ov) * tanhf_fast(ct);
                int row = (r & 3) + 8 * (r >> 2) + 4 * hi;   // verified C layout
                *(_Float16*)(hbuf + row * 128 + ((j * 2) ^ ((row & 7) << 4))) = (_Float16)hv;
            }
        }
    }

    // encoder-final h fragments (h region untouched by restaging)
    #pragma unroll
    for (int kk = 0; kk < 4; ++kk)
        haf[kk] = *(const f16x8*)(hbuf + cl * 128 + ((kk * 32 + hi * 16) ^ ((cl & 7) << 4)));

    // ---------------- restage decoder tables ----------------
    __syncthreads();   // all waves done reading enc tables
    for (int i = tid; i < 256 * 64; i += 256) {
        int n = i >> 6, k = i & 63;
        *(_Float16*)(lds + WOFF + n * 128 + (((k * 2) ^ ((n & 7) << 4)))) =
            (_Float16)(Wih_d[i] + Whh_d[i]);   // x==h -> combine
    }
    for (int i = tid; i < 32 * 64; i += 256) {
        int n = i >> 6, k = i & 63;
        float v = (n < 2) ? Wemb[n * 64 + k] : 0.0f;
        *(_Float16*)(lds + EMBOFF + n * 128 + (((k * 2) ^ ((n & 7) << 4)))) = (_Float16)v;
    }
    __syncthreads();

    // per-lane decoder bias (one per owned N-tile)
    float bdec_pl[8];
    #pragma unroll
    for (int t8 = 0; t8 < 8; ++t8) {
        int n = t8 * 32 + cl;
        bdec_pl[t8] = bih_d[n] + bhh_d[n];
    }
    float bemb_pl = (cl < 2) ? bemb[cl] : 0.0f;

    // ---------------- decoder: 30 steps ----------------
    for (int t = 1; t <= DEC_T; ++t) {
        #pragma unroll
        for (int t8 = 0; t8 < 8; ++t8) {
            #pragma unroll
            for (int q = 0; q < 16; ++q) acc[t8][q] = bdec_pl[t8];
        }
        #pragma unroll
        for (int kk = 0; kk < 4; ++kk) {
            #pragma unroll
            for (int t8 = 0; t8 < 8; ++t8) {
                int n = t8 * 32 + cl;
                f16x8 wb = *(const f16x8*)(lds + WOFF + n * 128 + ((kk * 32 + hi * 16) ^ ((n & 7) << 4)));
                acc[t8] = __builtin_amdgcn_mfma_f32_32x32x16_f16(haf[kk], wb, acc[t8], 0, 0, 0);
            }
        }
        #pragma unroll
        for (int js = 0; js < 2; ++js) {
            int j = cl + js * 32;
            #pragma unroll
            for (int r = 0; r < 16; ++r) {
                float iv = acc[0 + js][r];
                float fv = acc[2 + js][r];
                float gv = acc[4 + js][r];
                float ov = acc[6 + js][r];
                float cc = c[js * 16 + r];
                float ct = sigf(fv) * cc + sigf(iv) * tanhf_fast(gv);
                c[js * 16 + r] = ct;
                float hv = sigf(ov) * tanhf_fast(ct);
                int row = (r & 3) + 8 * (r >> 2) + 4 * hi;
                *(_Float16*)(hbuf + row * 128 + ((j * 2) ^ ((row & 7) << 4))) = (_Float16)hv;
            }
        }
        // fragments of the NEW h (feeds both pred below and next step's gates)
        #pragma unroll
        for (int kk = 0; kk < 4; ++kk)
            haf[kk] = *(const f16x8*)(hbuf + cl * 128 + ((kk * 32 + hi * 16) ^ ((cl & 7) << 4)));
        // pred_t = h_t @ Wemb^T + b_emb  (single 32-wide N-tile, cols 0,1 valid)
        f32x16 pacc;
        #pragma unroll
        for (int q = 0; q < 16; ++q) pacc[q] = 0.0f;
        #pragma unroll
        for (int kk = 0; kk < 4; ++kk) {
            f16x8 we = *(const f16x8*)(lds + EMBOFF + cl * 128 + ((kk * 32 + hi * 16) ^ ((cl & 7) << 4)));
            pacc = __builtin_amdgcn_mfma_f32_32x32x16_f16(haf[kk], we, pacc, 0, 0, 0);
        }
        if (cl < 2) {
            #pragma unroll
            for (int r = 0; r < 16; ++r) {
                int row = (r & 3) + 8 * (r >> 2) + 4 * hi;
                out[(size_t)(r0 + row) * (DEC_T * 2) + (t - 1) * 2 + cl] = pacc[r] + bemb_pl;
            }
        }
    }
}

extern "C" void kernel_launch(void* const* d_in, const int* in_sizes, int n_in,
                              void* d_out, int out_size, void* d_ws, size_t ws_size,
                              hipStream_t stream) {
    const float* xin   = (const float*)d_in[0];
    const float* Wih_e = (const float*)d_in[1];
    const float* Whh_e = (const float*)d_in[2];
    const float* bih_e = (const float*)d_in[3];
    const float* bhh_e = (const float*)d_in[4];
    const float* Wih_d = (const float*)d_in[5];
    const float* Whh_d = (const float*)d_in[6];
    const float* bih_d = (const float*)d_in[7];
    const float* bhh_d = (const float*)d_in[8];
    const float* Wemb  = (const float*)d_in[9];
    const float* bemb  = (const float*)d_in[10];
    float* outp = (float*)d_out;

    int B = in_sizes[0] / (ENC_T * 2);
    int nwg = (B + 127) / 128;
    lstm_s2s_kernel<<<dim3(nwg), dim3(256), 0, stream>>>(
        xin, Wih_e, Whh_e, bih_e, bhh_e, Wih_d, Whh_d, bih_d, bhh_d, Wemb, bemb, outp, B);
}

// Round 5
// 435.801 us; speedup vs baseline: 1.6449x; 1.6449x over previous
//
#include <hip/hip_runtime.h>

#define ENC_T 20
#define DEC_T 30

typedef _Float16 f16x8 __attribute__((ext_vector_type(8)));
typedef float f32x16 __attribute__((ext_vector_type(16)));

// LDS layout (bytes): union region for W tables, restaged enc->dec
#define WOFF   0        // [256][64] f16 swizzled: Whh_enc, then Wdec=Wih_dec+Whh_dec (32KB)
#define WXOFF  32768    // [256][16] f16: enc x-tile table (w0,w1,bias,0...) (8KB)
#define EMBOFF 40960    // [32][64]  f16: W_emb rows 0,1 + zeros (4KB)
#define HOFF   45056    // 4 waves x [32][64] f16 h buffers (16KB)
#define LDS_BYTES 61440

__device__ __forceinline__ float sigf(float x) {
    return __builtin_amdgcn_rcpf(1.0f + __builtin_amdgcn_exp2f(-1.44269504088896f * x));
}
__device__ __forceinline__ float tanhf_fast(float x) {
    return 2.0f * __builtin_amdgcn_rcpf(1.0f + __builtin_amdgcn_exp2f(-2.88539008177793f * x)) - 1.0f;
}

// NOTE: no min-waves bound. R3 showed __launch_bounds__(256,2) capped VGPR at 128,
// spilling acc[8] (128 f32) to scratch -> 860MB/dispatch HBM spill traffic (the
// whole 657us was spill-BW-bound). LDS (60KB/WG) already caps occupancy at
// 2 WG/CU, so a ~256-VGPR allocation costs no occupancy.
__global__ __launch_bounds__(256)
void lstm_s2s_kernel(const float* __restrict__ xin,
                     const float* __restrict__ Wih_e, const float* __restrict__ Whh_e,
                     const float* __restrict__ bih_e, const float* __restrict__ bhh_e,
                     const float* __restrict__ Wih_d, const float* __restrict__ Whh_d,
                     const float* __restrict__ bih_d, const float* __restrict__ bhh_d,
                     const float* __restrict__ Wemb, const float* __restrict__ bemb,
                     float* __restrict__ out, int B)
{
    __shared__ __align__(16) unsigned char lds[LDS_BYTES];
    const int tid  = threadIdx.x;
    const int wid  = tid >> 6;
    const int lane = tid & 63;
    const int cl   = lane & 31;   // column-within-tile / A row
    const int hi   = lane >> 5;   // k-half select
    const int r0   = blockIdx.x * 128 + wid * 32;
    if (r0 >= B) return;

    // ---------------- stage encoder tables ----------------
    for (int i = tid; i < 256 * 64; i += 256) {
        int n = i >> 6, k = i & 63;
        *(_Float16*)(lds + WOFF + n * 128 + (((k * 2) ^ ((n & 7) << 4)))) = (_Float16)Whh_e[i];
    }
    {   // x-tile table: k0=Wih[:,0], k1=Wih[:,1], k2=b_ih+b_hh, rest 0
        int n = tid;
        float b  = bih_e[n] + bhh_e[n];
        float w0 = Wih_e[n * 2 + 0], w1 = Wih_e[n * 2 + 1];
        #pragma unroll
        for (int k = 0; k < 16; ++k) {
            float v = (k == 0) ? w0 : (k == 1) ? w1 : (k == 2) ? b : 0.0f;
            *(_Float16*)(lds + WXOFF + n * 32 + (((k * 2) ^ ((n & 1) << 4)))) = (_Float16)v;
        }
    }
    for (int i = tid; i < 4 * 32 * 64; i += 256)   // zero h buffers (h0 = 0)
        *(_Float16*)(lds + HOFF + i * 2) = (_Float16)0.0f;
    __syncthreads();

    unsigned char* hbuf = lds + HOFF + wid * 4096;

    float c[32];
    #pragma unroll
    for (int i = 0; i < 32; ++i) c[i] = 0.0f;

    f32x16 acc[8];
    f16x8  haf[4];

    // ---------------- encoder: 20 steps ----------------
    for (int t = 0; t < ENC_T; ++t) {
        // A fragment for x-tile: [x0, x1, 1, 0...] on low lanes, zeros on high lanes
        f16x8 xa;
        #pragma unroll
        for (int e = 0; e < 8; ++e) xa[e] = (_Float16)0.0f;
        if (hi == 0) {
            const float* xp = xin + (size_t)(r0 + cl) * (ENC_T * 2) + t * 2;
            xa[0] = (_Float16)xp[0];
            xa[1] = (_Float16)xp[1];
            xa[2] = (_Float16)1.0f;
        }
        #pragma unroll
        for (int t8 = 0; t8 < 8; ++t8) {
            int n = t8 * 32 + cl;
            f16x8 wx = *(const f16x8*)(lds + WXOFF + n * 32 + ((hi * 16) ^ ((n & 1) << 4)));
            f32x16 z;
            #pragma unroll
            for (int q = 0; q < 16; ++q) z[q] = 0.0f;
            acc[t8] = __builtin_amdgcn_mfma_f32_32x32x16_f16(xa, wx, z, 0, 0, 0);
        }
        #pragma unroll
        for (int kk = 0; kk < 4; ++kk)
            haf[kk] = *(const f16x8*)(hbuf + cl * 128 + ((kk * 32 + hi * 16) ^ ((cl & 7) << 4)));
        #pragma unroll
        for (int kk = 0; kk < 4; ++kk) {
            #pragma unroll
            for (int t8 = 0; t8 < 8; ++t8) {
                int n = t8 * 32 + cl;
                f16x8 wb = *(const f16x8*)(lds + WOFF + n * 128 + ((kk * 32 + hi * 16) ^ ((n & 7) << 4)));
                acc[t8] = __builtin_amdgcn_mfma_f32_32x32x16_f16(haf[kk], wb, acc[t8], 0, 0, 0);
            }
        }
        // elementwise LSTM cell; lane owns j in {cl, cl+32} x 16 rows
        #pragma unroll
        for (int js = 0; js < 2; ++js) {
            int j = cl + js * 32;
            #pragma unroll
            for (int r = 0; r < 16; ++r) {
                float iv = acc[0 + js][r];
                float fv = acc[2 + js][r];
                float gv = acc[4 + js][r];
                float ov = acc[6 + js][r];
                float cc = c[js * 16 + r];
                float ct = sigf(fv) * cc + sigf(iv) * tanhf_fast(gv);
                c[js * 16 + r] = ct;
                float hv = sigf(ov) * tanhf_fast(ct);
                int row = (r & 3) + 8 * (r >> 2) + 4 * hi;   // verified C layout
                *(_Float16*)(hbuf + row * 128 + ((j * 2) ^ ((row & 7) << 4))) = (_Float16)hv;
            }
        }
    }

    // encoder-final h fragments (h region untouched by restaging)
    #pragma unroll
    for (int kk = 0; kk < 4; ++kk)
        haf[kk] = *(const f16x8*)(hbuf + cl * 128 + ((kk * 32 + hi * 16) ^ ((cl & 7) << 4)));

    // ---------------- restage decoder tables ----------------
    __syncthreads();   // all waves done reading enc tables
    for (int i = tid; i < 256 * 64; i += 256) {
        int n = i >> 6, k = i & 63;
        *(_Float16*)(lds + WOFF + n * 128 + (((k * 2) ^ ((n & 7) << 4)))) =
            (_Float16)(Wih_d[i] + Whh_d[i]);   // x==h -> combine
    }
    for (int i = tid; i < 32 * 64; i += 256) {
        int n = i >> 6, k = i & 63;
        float v = (n < 2) ? Wemb[n * 64 + k] : 0.0f;
        *(_Float16*)(lds + EMBOFF + n * 128 + (((k * 2) ^ ((n & 7) << 4)))) = (_Float16)v;
    }
    __syncthreads();

    // per-lane decoder bias (one per owned N-tile)
    float bdec_pl[8];
    #pragma unroll
    for (int t8 = 0; t8 < 8; ++t8) {
        int n = t8 * 32 + cl;
        bdec_pl[t8] = bih_d[n] + bhh_d[n];
    }
    float bemb_pl = (cl < 2) ? bemb[cl] : 0.0f;

    // ---------------- decoder: 30 steps ----------------
    for (int t = 1; t <= DEC_T; ++t) {
        #pragma unroll
        for (int t8 = 0; t8 < 8; ++t8) {
            #pragma unroll
            for (int q = 0; q < 16; ++q) acc[t8][q] = bdec_pl[t8];
        }
        #pragma unroll
        for (int kk = 0; kk < 4; ++kk) {
            #pragma unroll
            for (int t8 = 0; t8 < 8; ++t8) {
                int n = t8 * 32 + cl;
                f16x8 wb = *(const f16x8*)(lds + WOFF + n * 128 + ((kk * 32 + hi * 16) ^ ((n & 7) << 4)));
                acc[t8] = __builtin_amdgcn_mfma_f32_32x32x16_f16(haf[kk], wb, acc[t8], 0, 0, 0);
            }
        }
        #pragma unroll
        for (int js = 0; js < 2; ++js) {
            int j = cl + js * 32;
            #pragma unroll
            for (int r = 0; r < 16; ++r) {
                float iv = acc[0 + js][r];
                float fv = acc[2 + js][r];
                float gv = acc[4 + js][r];
                float ov = acc[6 + js][r];
                float cc = c[js * 16 + r];
                float ct = sigf(fv) * cc + sigf(iv) * tanhf_fast(gv);
                c[js * 16 + r] = ct;
                float hv = sigf(ov) * tanhf_fast(ct);
                int row = (r & 3) + 8 * (r >> 2) + 4 * hi;
                *(_Float16*)(hbuf + row * 128 + ((j * 2) ^ ((row & 7) << 4))) = (_Float16)hv;
            }
        }
        // fragments of the NEW h (feeds both pred below and next step's gates)
        #pragma unroll
        for (int kk = 0; kk < 4; ++kk)
            haf[kk] = *(const f16x8*)(hbuf + cl * 128 + ((kk * 32 + hi * 16) ^ ((cl & 7) << 4)));
        // pred_t = h_t @ Wemb^T + b_emb  (single 32-wide N-tile, cols 0,1 valid)
        f32x16 pacc;
        #pragma unroll
        for (int q = 0; q < 16; ++q) pacc[q] = 0.0f;
        #pragma unroll
        for (int kk = 0; kk < 4; ++kk) {
            f16x8 we = *(const f16x8*)(lds + EMBOFF + cl * 128 + ((kk * 32 + hi * 16) ^ ((cl & 7) << 4)));
            pacc = __builtin_amdgcn_mfma_f32_32x32x16_f16(haf[kk], we, pacc, 0, 0, 0);
        }
        if (cl < 2) {
            #pragma unroll
            for (int r = 0; r < 16; ++r) {
                int row = (r & 3) + 8 * (r >> 2) + 4 * hi;
                out[(size_t)(r0 + row) * (DEC_T * 2) + (t - 1) * 2 + cl] = pacc[r] + bemb_pl;
            }
        }
    }
}

extern "C" void kernel_launch(void* const* d_in, const int* in_sizes, int n_in,
                              void* d_out, int out_size, void* d_ws, size_t ws_size,
                              hipStream_t stream) {
    const float* xin   = (const float*)d_in[0];
    const float* Wih_e = (const float*)d_in[1];
    const float* Whh_e = (const float*)d_in[2];
    const float* bih_e = (const float*)d_in[3];
    const float* bhh_e = (const float*)d_in[4];
    const float* Wih_d = (const float*)d_in[5];
    const float* Whh_d = (const float*)d_in[6];
    const float* bih_d = (const float*)d_in[7];
    const float* bhh_d = (const float*)d_in[8];
    const float* Wemb  = (const float*)d_in[9];
    const float* bemb  = (const float*)d_in[10];
    float* outp = (float*)d_out;

    int B = in_sizes[0] / (ENC_T * 2);
    int nwg = (B + 127) / 128;
    lstm_s2s_kernel<<<dim3(nwg), dim3(256), 0, stream>>>(
        xin, Wih_e, Whh_e, bih_e, bhh_e, Wih_d, Whh_d, bih_d, bhh_d, Wemb, bemb, outp, B);
}

// Round 7
// 331.870 us; speedup vs baseline: 2.1600x; 1.3132x over previous
//
#include <hip/hip_runtime.h>

#define ENC_T 20
#define DEC_T 30

typedef _Float16 f16x8 __attribute__((ext_vector_type(8)));
typedef _Float16 f16x2 __attribute__((ext_vector_type(2)));
typedef float f32x16 __attribute__((ext_vector_type(16)));

// LDS layout (bytes):
//   WOFF: [256 n][64 k] f16, row-swizzled: byte = n*128 + ((2k) ^ ((n&7)<<4))
//         holds Whh_enc, restaged to Wih_dec+Whh_dec for the decoder.
//   WXOFF: [256][2] f16 (Wih_enc cols 0,1) - 1KB
//   HOFF: 4 waves x [32 row][64 j] f16, swizzled like W rows (4KB each)
#define WOFF   0
#define WXOFF  32768
#define HOFF   33792
#define LDS_BYTES 50176

// sigmoid(x + b) with cs = -log2(e)*b pre-folded into the fma (bias is free)
__device__ __forceinline__ float sig_c(float x, float cs) {
    return __builtin_amdgcn_rcpf(1.0f + __builtin_amdgcn_exp2f(__builtin_fmaf(-1.442695040f, x, cs)));
}
// tanh(x + b) with cs = -2*log2(e)*b
__device__ __forceinline__ float tanh_c(float x, float cs) {
    return __builtin_fmaf(2.0f, __builtin_amdgcn_rcpf(1.0f + __builtin_amdgcn_exp2f(__builtin_fmaf(-2.885390081f, x, cs))), -1.0f);
}
__device__ __forceinline__ float tanh_n(float x) {
    return __builtin_fmaf(2.0f, __builtin_amdgcn_rcpf(1.0f + __builtin_amdgcn_exp2f(-2.885390081f * x)), -1.0f);
}

// (256,2): unified VGPR+AGPR budget 256/wave -> 2 waves/SIMD (R5 was 1 wave at
// 348 total). Arch-live now ~115 (addressing hoisted to 8 base regs; biases
// fma-folded; Wemb in regs) + acc[8]=128 AGPR. Spill sentinel: FETCH_SIZE.
//
// K-pairing note (bug caught in audit): fragment reads must deliver the SAME
// original k-chunk to every lane of one MFMA. The XOR swizzle's bits 5-6
// (cc2=(cl>>1)&3, per-lane!) therefore CANNOT be folded into additive
// immediates; instead each chunk m gets a precomputed base ha[m]/wa[m] =
// rb + ((m^cc2)<<5) (bits 5-6 of rb are zero, so + == ^). Addresses are then
// bit-identical to the R5-verified kernel, with zero per-step address VALU.
__global__ __launch_bounds__(256, 2)
void lstm_s2s_kernel(const float* __restrict__ xin,
                     const float* __restrict__ Wih_e, const float* __restrict__ Whh_e,
                     const float* __restrict__ bih_e, const float* __restrict__ bhh_e,
                     const float* __restrict__ Wih_d, const float* __restrict__ Whh_d,
                     const float* __restrict__ bih_d, const float* __restrict__ bhh_d,
                     const float* __restrict__ Wemb, const float* __restrict__ bemb,
                     float* __restrict__ out, int B)
{
    __shared__ __align__(16) unsigned char lds[LDS_BYTES];
    const int tid  = threadIdx.x;
    const int wid  = tid >> 6;
    const int lane = tid & 63;
    const int cl   = lane & 31;        // C col within tile / A row
    const int hi   = lane >> 5;        // k-half select
    const int hi2  = hi ^ (cl & 1);    // bit4 of swizzle const folded into base
    const int cc2  = (cl >> 1) & 3;    // bits 5-6 of swizzle const
    const int r0   = blockIdx.x * 128 + wid * 32;

    // ---------------- stage encoder tables ----------------
    for (int i = tid; i < 256 * 64; i += 256) {
        int n = i >> 6, k = i & 63;
        *(_Float16*)(lds + WOFF + n * 128 + ((k * 2) ^ ((n & 7) << 4))) = (_Float16)Whh_e[i];
    }
    {
        f16x2 w;
        w[0] = (_Float16)Wih_e[tid * 2 + 0];
        w[1] = (_Float16)Wih_e[tid * 2 + 1];
        *(f16x2*)(lds + WXOFF + tid * 4) = w;
    }

    // per-lane bias constants, fma-folded (enc). Lane's j = cl + js*32.
    float csI[2], csF[2], csG[2], csO[2];
    #pragma unroll
    for (int js = 0; js < 2; ++js) {
        int j = cl + js * 32;
        csI[js] = -1.442695040f * (bih_e[0 * 64 + j] + bhh_e[0 * 64 + j]);
        csF[js] = -1.442695040f * (bih_e[1 * 64 + j] + bhh_e[1 * 64 + j]);
        csG[js] = -2.885390081f * (bih_e[2 * 64 + j] + bhh_e[2 * 64 + j]);
        csO[js] = -1.442695040f * (bih_e[3 * 64 + j] + bhh_e[3 * 64 + j]);
    }
    __syncthreads();

    // Per-chunk read bases (canonical chunk m for EVERY lane -> correct MFMA
    // K-pairing). Inner-loop variation (t8) is a compile-time immediate.
    const unsigned rb_h = HOFF + wid * 4096 + cl * 128 + hi2 * 16;
    const unsigned rb_w = WOFF + cl * 128 + hi2 * 16;
    const unsigned rb_x = WXOFF + cl * 4;
    unsigned ha[4], wa[4];
    #pragma unroll
    for (int m = 0; m < 4; ++m) {
        ha[m] = rb_h + (unsigned)((m ^ cc2) << 5);
        wa[m] = rb_w + (unsigned)((m ^ cc2) << 5);
    }

    // h-write byte addr = hwb[js][r&3] + ((r&3)*128 + (r>>2)*1024)   [imm]
    unsigned hwb[2][4];
    #pragma unroll
    for (int js = 0; js < 2; ++js)
        #pragma unroll
        for (int v = 0; v < 4; ++v)
            hwb[js][v] = HOFF + wid * 4096 + hi * 512
                       + (((unsigned)(2 * cl)) ^ (v << 4)) + (((js ^ hi) & 1) << 6);

    float c[32];
    #pragma unroll
    for (int i = 0; i < 32; ++i) c[i] = 0.0f;

    f16x8 haf[4];                       // h0 = 0: no LDS pre-zero needed
    #pragma unroll
    for (int m = 0; m < 4; ++m)
        #pragma unroll
        for (int e = 0; e < 8; ++e) haf[m][e] = (_Float16)0.0f;

    f32x16 zz;
    #pragma unroll
    for (int q = 0; q < 16; ++q) zz[q] = 0.0f;

    // ---------------- encoder: 20 steps ----------------
    for (int t = 0; t < ENC_T; ++t) {
        const float* xp = xin + (size_t)(r0 + cl) * (ENC_T * 2) + t * 2;
        float x0 = xp[0], x1 = xp[1];
        f16x8 xa;
        #pragma unroll
        for (int e = 0; e < 8; ++e) xa[e] = (_Float16)0.0f;
        xa[0] = hi ? (_Float16)0.0f : (_Float16)x0;
        xa[1] = hi ? (_Float16)0.0f : (_Float16)x1;

        f32x16 acc[8];
        #pragma unroll
        for (int t8 = 0; t8 < 8; ++t8) {
            f16x2 wxv = *(const f16x2*)(lds + rb_x + t8 * 128);
            f16x8 wx;
            #pragma unroll
            for (int e = 0; e < 8; ++e) wx[e] = (_Float16)0.0f;
            wx[0] = hi ? (_Float16)0.0f : wxv[0];
            wx[1] = hi ? (_Float16)0.0f : wxv[1];
            acc[t8] = __builtin_amdgcn_mfma_f32_32x32x16_f16(xa, wx, zz, 0, 0, 0);
        }
        #pragma unroll
        for (int m = 0; m < 4; ++m)
            #pragma unroll
            for (int t8 = 0; t8 < 8; ++t8) {
                f16x8 wb = *(const f16x8*)(lds + wa[m] + t8 * 4096);
                acc[t8] = __builtin_amdgcn_mfma_f32_32x32x16_f16(haf[m], wb, acc[t8], 0, 0, 0);
            }

        #pragma unroll
        for (int js = 0; js < 2; ++js) {
            #pragma unroll
            for (int r = 0; r < 16; ++r) {
                float iv = acc[0 + js][r];
                float fv = acc[2 + js][r];
                float gv = acc[4 + js][r];
                float ov = acc[6 + js][r];
                float cc = c[js * 16 + r];
                float si = sig_c(iv, csI[js]);
                float sf = sig_c(fv, csF[js]);
                float tg = tanh_c(gv, csG[js]);
                float ct = __builtin_fmaf(sf, cc, si * tg);
                c[js * 16 + r] = ct;
                float hv = sig_c(ov, csO[js]) * tanh_n(ct);
                *(_Float16*)(lds + hwb[js][r & 3] + ((r & 3) * 128 + (r >> 2) * 1024)) = (_Float16)hv;
            }
        }
        // DS ops complete in order within a wave: read-after-write is safe
        #pragma unroll
        for (int m = 0; m < 4; ++m)
            haf[m] = *(const f16x8*)(lds + ha[m]);
    }

    // ---------------- restage decoder tables ----------------
    __syncthreads();   // all waves done reading enc W
    for (int i = tid; i < 256 * 64; i += 256) {
        int n = i >> 6, k = i & 63;
        *(_Float16*)(lds + WOFF + n * 128 + ((k * 2) ^ ((n & 7) << 4))) =
            (_Float16)(Wih_d[i] + Whh_d[i]);   // x==h -> combine
    }
    #pragma unroll
    for (int js = 0; js < 2; ++js) {
        int j = cl + js * 32;
        csI[js] = -1.442695040f * (bih_d[0 * 64 + j] + bhh_d[0 * 64 + j]);
        csF[js] = -1.442695040f * (bih_d[1 * 64 + j] + bhh_d[1 * 64 + j]);
        csG[js] = -2.885390081f * (bih_d[2 * 64 + j] + bhh_d[2 * 64 + j]);
        csO[js] = -1.442695040f * (bih_d[3 * 64 + j] + bhh_d[3 * 64 + j]);
    }
    // Wemb fragments in registers, canonical chunk order (B[k][col]=Wemb[col][k];
    // cols 2..31 hold duplicates of cols 0/1 - those pacc cols are never stored).
    f16x8 we[4];
    {
        const float* wr = Wemb + (size_t)(cl & 1) * 64;
        #pragma unroll
        for (int m = 0; m < 4; ++m) {
            int k0 = m * 16 + hi * 8;
            #pragma unroll
            for (int e = 0; e < 8; ++e) we[m][e] = (_Float16)wr[k0 + e];
        }
    }
    float bemb_pl = (cl < 2) ? bemb[cl] : 0.0f;
    __syncthreads();

    // ---------------- decoder: 30 steps ----------------
    for (int t = 1; t <= DEC_T; ++t) {
        f32x16 acc[8];
        #pragma unroll
        for (int t8 = 0; t8 < 8; ++t8) {
            f16x8 wb = *(const f16x8*)(lds + wa[0] + t8 * 4096);
            acc[t8] = __builtin_amdgcn_mfma_f32_32x32x16_f16(haf[0], wb, zz, 0, 0, 0);
        }
        #pragma unroll
        for (int m = 1; m < 4; ++m)
            #pragma unroll
            for (int t8 = 0; t8 < 8; ++t8) {
                f16x8 wb = *(const f16x8*)(lds + wa[m] + t8 * 4096);
                acc[t8] = __builtin_amdgcn_mfma_f32_32x32x16_f16(haf[m], wb, acc[t8], 0, 0, 0);
            }

        #pragma unroll
        for (int js = 0; js < 2; ++js) {
            #pragma unroll
            for (int r = 0; r < 16; ++r) {
                float iv = acc[0 + js][r];
                float fv = acc[2 + js][r];
                float gv = acc[4 + js][r];
                float ov = acc[6 + js][r];
                float cc = c[js * 16 + r];
                float si = sig_c(iv, csI[js]);
                float sf = sig_c(fv, csF[js]);
                float tg = tanh_c(gv, csG[js]);
                float ct = __builtin_fmaf(sf, cc, si * tg);
                c[js * 16 + r] = ct;
                float hv = sig_c(ov, csO[js]) * tanh_n(ct);
                *(_Float16*)(lds + hwb[js][r & 3] + ((r & 3) * 128 + (r >> 2) * 1024)) = (_Float16)hv;
            }
        }
        #pragma unroll
        for (int m = 0; m < 4; ++m)
            haf[m] = *(const f16x8*)(lds + ha[m]);

        // pred_t = h_t @ Wemb^T + b_emb  (Wemb fragments in registers)
        f32x16 pacc = __builtin_amdgcn_mfma_f32_32x32x16_f16(haf[0], we[0], zz, 0, 0, 0);
        #pragma unroll
        for (int m = 1; m < 4; ++m)
            pacc = __builtin_amdgcn_mfma_f32_32x32x16_f16(haf[m], we[m], pacc, 0, 0, 0);

        if (cl < 2) {
            #pragma unroll
            for (int r = 0; r < 16; ++r) {
                int row = (r & 3) + 8 * (r >> 2) + 4 * hi;
                out[(size_t)(r0 + row) * (DEC_T * 2) + (t - 1) * 2 + cl] = pacc[r] + bemb_pl;
            }
        }
    }
}

extern "C" void kernel_launch(void* const* d_in, const int* in_sizes, int n_in,
                              void* d_out, int out_size, void* d_ws, size_t ws_size,
                              hipStream_t stream) {
    const float* xin   = (const float*)d_in[0];
    const float* Wih_e = (const float*)d_in[1];
    const float* Whh_e = (const float*)d_in[2];
    const float* bih_e = (const float*)d_in[3];
    const float* bhh_e = (const float*)d_in[4];
    const float* Wih_d = (const float*)d_in[5];
    const float* Whh_d = (const float*)d_in[6];
    const float* bih_d = (const float*)d_in[7];
    const float* bhh_d = (const float*)d_in[8];
    const float* Wemb  = (const float*)d_in[9];
    const float* bemb  = (const float*)d_in[10];
    float* outp = (float*)d_out;

    int B = in_sizes[0] / (ENC_T * 2);
    int nwg = (B + 127) / 128;
    lstm_s2s_kernel<<<dim3(nwg), dim3(256), 0, stream>>>(
        xin, Wih_e, Whh_e, bih_e, bhh_e, Wih_d, Whh_d, bih_d, bhh_d, Wemb, bemb, outp, B);
}